// Round 15
// baseline (7175.150 us; speedup 1.0000x reference)
//
#include <hip/hip_runtime.h>
#include <math.h>

#define B_ 64
#define T_ 2048
#define D_ 512
#define BT_ (B_ * T_)   // 131072
#define XWORDS (B_ * D_)   // 32768 8-byte words per parity slot: [batch][512]

typedef unsigned long long u64;
typedef float f32x4 __attribute__((ext_vector_type(4)));   // nontemporal-ok

// ---------------------------------------------------------------------------
// Kernel 1: weight prep (transpose to k-major for coalesced GEMM/GEMV reads)
// ---------------------------------------------------------------------------
__global__ void prep_weights(const float* __restrict__ tau_w,
                             const float* __restrict__ mem_w,
                             float* __restrict__ Wcat,
                             float* __restrict__ WTh) {
    int idx = blockIdx.x * 256 + threadIdx.x;   // 0 .. 524287
    {
        int k = idx >> 10, j = idx & 1023;
        float v = (j < 512) ? tau_w[j * 1024 + k] : mem_w[(j - 512) * 512 + k];
        Wcat[idx] = v;
    }
    if (idx < 512 * 512) {
        int k = idx >> 9, d = idx & 511;
        WTh[idx] = tau_w[d * 1024 + 512 + k];
    }
}

// ---------------------------------------------------------------------------
// Kernel 2: f32 GEMM  C[131072][1024] = X[131072][512] @ Wcat[512][1024] + bias
// ---------------------------------------------------------------------------
__global__ __launch_bounds__(256, 2)
void gemm_xw(const float* __restrict__ X, const float* __restrict__ Wc,
             const float* __restrict__ tau_b, const float* __restrict__ mem_b,
             float* __restrict__ Aout, float* __restrict__ Mout) {
    __shared__ __align__(16) float As[16][128];  // [k][m]
    __shared__ __align__(16) float Bs[16][128];  // [k][n]
    const int bn = blockIdx.x;          // 0..7
    const int bm = blockIdx.y;          // 0..1023
    const int tid = threadIdx.x;
    const int tm = (tid >> 4) << 3;
    const int tn = (tid & 15) << 3;
    const int m0 = bm * 128, n0 = bn * 128;

    const float4* X4 = (const float4*)X;
    const float4* Wc4 = (const float4*)Wc;

    float acc[8][8];
#pragma unroll
    for (int i = 0; i < 8; i++)
#pragma unroll
        for (int j = 0; j < 8; j++) acc[i][j] = 0.0f;

    const int ar = tid >> 1;              // 0..127 row in tile
    const int ac2 = (tid & 1) * 2;        // float4 col 0 or 2
    const int bkr = tid >> 4;             // 0..15
    const int bc = (tid & 15) * 2;        // float4 col 0..30

    for (int kt = 0; kt < 512; kt += 16) {
        float4 av0 = X4[(m0 + ar) * 128 + (kt >> 2) + ac2];
        float4 av1 = X4[(m0 + ar) * 128 + (kt >> 2) + ac2 + 1];
        float4 bv0 = Wc4[(kt + bkr) * 256 + bn * 32 + bc];
        float4 bv1 = Wc4[(kt + bkr) * 256 + bn * 32 + bc + 1];
        __syncthreads();   // protect previous iteration's reads
        As[ac2 * 4 + 0][ar] = av0.x;
        As[ac2 * 4 + 1][ar] = av0.y;
        As[ac2 * 4 + 2][ar] = av0.z;
        As[ac2 * 4 + 3][ar] = av0.w;
        As[ac2 * 4 + 4][ar] = av1.x;
        As[ac2 * 4 + 5][ar] = av1.y;
        As[ac2 * 4 + 6][ar] = av1.z;
        As[ac2 * 4 + 7][ar] = av1.w;
        *(float4*)&Bs[bkr][bc * 4] = bv0;
        *(float4*)&Bs[bkr][bc * 4 + 4] = bv1;
        __syncthreads();
#pragma unroll
        for (int kk = 0; kk < 16; kk++) {
            float4 a0 = *(const float4*)&As[kk][tm];
            float4 a1 = *(const float4*)&As[kk][tm + 4];
            float4 b0 = *(const float4*)&Bs[kk][tn];
            float4 b1 = *(const float4*)&Bs[kk][tn + 4];
            float av[8] = {a0.x, a0.y, a0.z, a0.w, a1.x, a1.y, a1.z, a1.w};
            float bv[8] = {b0.x, b0.y, b0.z, b0.w, b1.x, b1.y, b1.z, b1.w};
#pragma unroll
            for (int i = 0; i < 8; i++)
#pragma unroll
                for (int j = 0; j < 8; j++)
                    acc[i][j] = fmaf(av[i], bv[j], acc[i][j]);
        }
    }

    const bool isA = (bn < 4);
    float* Cout = isA ? Aout : Mout;
    const float* bias = isA ? tau_b : mem_b;
    const int ncol0 = (isA ? n0 : n0 - 512) + tn;
    float bj[8];
#pragma unroll
    for (int j = 0; j < 8; j++) bj[j] = bias[ncol0 + j];
#pragma unroll
    for (int i = 0; i < 8; i++) {
        size_t off = (size_t)(m0 + tm + i) * 512 + ncol0;
        f32x4 o0, o1;
        o0.x = acc[i][0] + bj[0]; o0.y = acc[i][1] + bj[1];
        o0.z = acc[i][2] + bj[2]; o0.w = acc[i][3] + bj[3];
        o1.x = acc[i][4] + bj[4]; o1.y = acc[i][5] + bj[5];
        o1.z = acc[i][6] + bj[6]; o1.w = acc[i][7] + bj[7];
        __builtin_nontemporal_store(o0, (f32x4*)&Cout[off]);
        __builtin_nontemporal_store(o1, (f32x4*)&Cout[off + 4]);
    }
}

// ---------------------------------------------------------------------------
// Kernel 3: reset sync state every launch (graph-replay safe).
// Slot0 words = {seq=0, tau=1.0} (the t=0 carry); slot1 words = {seq=0, *}.
// ---------------------------------------------------------------------------
__global__ void init_sync(u64* __restrict__ xchg, int* __restrict__ ctr) {
    int idx = blockIdx.x * 256 + threadIdx.x;   // 0 .. 65535
    if (idx < 2 * XWORDS) xchg[idx] = (idx < XWORDS) ? 0x3F800000ull : 0ull;
    if (idx < 16) ctr[idx] = 0;
}

// ---------------------------------------------------------------------------
// Kernel 4: cooperative scan — wave-sg-owned epilogue, 1 barrier, in-register
// recurrent state, agent-scope exchange (the only proven-visible primitive:
// r13/r14 showed plain and sc0 stores never become visible cross-CU).
//
// Key round-15 restructure: the epilogue (sum partials -> tau -> publish ->
// v/spike) belongs to WAVE sg (lane = channel, 2 batches/lane) instead of
// tid<128. Consequences:
//  - wave sg's tau stays in registers across steps (lane l holds
//    tau[sg*64+l] — exactly the poll layout) -> no self-poll (r10's
//    regression), no tau_sm LDS, uniform readlane FMA path;
//  - ONE barrier/step: part[] parity-dbuf; slot reuse at c+2 is ordered
//    transitively (our publish(c) follows sg's part(c) read; partners
//    can't reach c+2 without it);
//  - non-sg waves go straight from barrier to polling, overlapping
//    partner visibility with our FMA issue.
// FMA/readlane and 8-slot sum orders are bit-identical to r12 (passed).
// ---------------------------------------------------------------------------
__global__ __launch_bounds__(512)
__attribute__((amdgpu_waves_per_eu(2, 2)))
void scan_ws(const float* __restrict__ WTh,
             const float* __restrict__ Mm,
             const float* __restrict__ log_thresh,
             float* __restrict__ AmOut,   // A in / spikes out (d_out)
             float* __restrict__ OutTail, // d_out base for tau/v tails
             u64* __restrict__ xchg,
             int* __restrict__ ctr) {
    __shared__ __align__(16) float4 w_lds[8192];       // 128 KB
    __shared__ __align__(16) float part[2][2][8][64];  // 16 KB [par][b][slot][ch]
    __shared__ int role_s;

    const int tid = threadIdx.x;

    if (tid == 0) {
        unsigned xcd;
        asm volatile("s_getreg_b32 %0, hwreg(HW_REG_XCC_ID)" : "=s"(xcd));
        xcd &= 7;
        int rank = atomicAdd(&ctr[xcd], 1) & 31;
        role_s = ((rank & 7) << 8) | ((int)xcd * 4 + (rank >> 3));
    }
    __syncthreads();
    const int sg = role_s >> 8;    // channel segment 0..7
    const int bp = role_s & 255;   // batch pair 0..31

    // ---- stage weight slice into LDS (one-time, 128 KB) ----
    {
        const int ch = tid & 63;
        const int kr8 = tid >> 6;          // 0..7
        float* wl = (float*)w_lds;
        for (int i = 0; i < 64; i++) {
            int krow = i * 8 + kr8;
            wl[(krow >> 2) * 256 + ch * 4 + (krow & 3)] =
                WTh[krow * 512 + sg * 64 + ch];
        }
    }

    const int ws = tid >> 6;       // wave = k-window [ws*64,+64) = segment ws
    const int lane = tid & 63;     // lane = channel within the window/output
    const bool self = (ws == sg);
    const int gch = sg * 64 + lane;   // epilogue channel (wave sg, lane=ch)

    // wave-sg per-lane recurrent state (2 batches)
    float thr = 0.f, v0 = 0.f, v1 = 0.f, tk0 = 1.0f, tk1 = 1.0f;
    size_t ab0 = 0, ab1 = 0;
    float a0_pf = 0.f, m0_pf = 0.f, a1_pf = 0.f, m1_pf = 0.f;
    if (self) {
        thr = 1.0f / (1.0f + expf(-log_thresh[gch]));
        ab0 = (size_t)(bp * 2) * T_ * D_ + gch;
        ab1 = ab0 + (size_t)T_ * D_;
        a0_pf = __builtin_nontemporal_load(&AmOut[ab0]);
        m0_pf = __builtin_nontemporal_load(&Mm[ab0]);
        a1_pf = __builtin_nontemporal_load(&AmOut[ab1]);
        m1_pf = __builtin_nontemporal_load(&Mm[ab1]);
    }
    __syncthreads();   // weights staged

    int t0i = 0x3F800000, t1i = 0x3F800000;   // t=0 carry (tau = 1.0)

    for (int c = 1; c <= T_; c++) {
        // ---- acquire tau_{c-1} for this wave's segment ----
        if (!self) {
            const u64* s0 = xchg + (size_t)((c - 1) & 1) * XWORDS
                                 + (size_t)(bp * 2) * 512 + ws * 64 + lane;
            const u64* s1 = s0 + 512;   // batch 1 of the pair
            const unsigned tgt = (unsigned)(c - 1);
            u64 w0, w1;
            int guard = 0;
            do {
                w0 = __hip_atomic_load(s0, __ATOMIC_RELAXED,
                                       __HIP_MEMORY_SCOPE_AGENT);
                w1 = __hip_atomic_load(s1, __ATOMIC_RELAXED,
                                       __HIP_MEMORY_SCOPE_AGENT);
            } while ((((unsigned)(w0 >> 32) < tgt) |
                      ((unsigned)(w1 >> 32) < tgt)) && ++guard < (1 << 16));
            t0i = (int)(unsigned)w0;
            t1i = (int)(unsigned)w1;
        }
        // (wave sg: t0i/t1i already hold its own tau from last epilogue)

        // ---- FMA over own 64-k window: LDS weights + readlane tau ----
        float acc0 = 0.f, acc1 = 0.f;
#pragma unroll
        for (int q4 = 0; q4 < 16; q4++) {
            float4 wv = w_lds[(ws * 16 + q4) * 64 + lane];
#pragma unroll
            for (int j = 0; j < 4; j++) {
                const int kk = q4 * 4 + j;
                const float wj = (j == 0) ? wv.x : (j == 1) ? wv.y
                               : (j == 2) ? wv.z : wv.w;
                float ta = __uint_as_float(
                    (unsigned)__builtin_amdgcn_readlane(t0i, kk));
                float tb = __uint_as_float(
                    (unsigned)__builtin_amdgcn_readlane(t1i, kk));
                acc0 = fmaf(ta, wj, acc0);
                acc1 = fmaf(tb, wj, acc1);
            }
        }
        const int par = c & 1;
        part[par][0][ws][lane] = acc0;
        part[par][1][ws][lane] = acc1;
        __syncthreads();   // the ONLY barrier: partials of step c ready

        // ---- epilogue on wave sg only; others proceed to next poll ----
        if (self) {
            // prefetch next step's A/M first (overlaps the LDS sum reads)
            float a0_nx = 0.f, m0_nx = 0.f, a1_nx = 0.f, m1_nx = 0.f;
            if (c < T_) {
                a0_nx = __builtin_nontemporal_load(&AmOut[ab0 + D_]);
                m0_nx = __builtin_nontemporal_load(&Mm[ab0 + D_]);
                a1_nx = __builtin_nontemporal_load(&AmOut[ab1 + D_]);
                m1_nx = __builtin_nontemporal_load(&Mm[ab1 + D_]);
            }
            float s0 = 0.f, s1 = 0.f;
#pragma unroll
            for (int j = 0; j < 8; j++) s0 += part[par][0][j][lane];
#pragma unroll
            for (int j = 0; j < 8; j++) s1 += part[par][1][j][lane];
            float tau0 = 1.0f / (1.0f + expf(-(s0 + a0_pf)));
            float tau1 = 1.0f / (1.0f + expf(-(s1 + a1_pf)));
            // publish FIRST (inter-block critical path), tail after
            u64 base = (size_t)(c & 1) * XWORDS + (size_t)(bp * 2) * 512 + gch;
            __hip_atomic_store(&xchg[base],
                               ((u64)(unsigned)c << 32) | (u64)__float_as_uint(tau0),
                               __ATOMIC_RELAXED, __HIP_MEMORY_SCOPE_AGENT);
            __hip_atomic_store(&xchg[base + 512],
                               ((u64)(unsigned)c << 32) | (u64)__float_as_uint(tau1),
                               __ATOMIC_RELAXED, __HIP_MEMORY_SCOPE_AGENT);
            // off-critical-path tail: v / spike / stores
            float al0 = expf(-1.0f / (tau0 + 1e-6f));
            float al1 = expf(-1.0f / (tau1 + 1e-6f));
            v0 = al0 * v0 + (1.0f - al0) * m0_pf;
            v1 = al1 * v1 + (1.0f - al1) * m1_pf;
            float sp0 = (v0 >= thr) ? 1.0f : 0.0f;
            float sp1 = (v1 >= thr) ? 1.0f : 0.0f;
            __builtin_nontemporal_store(sp0, &AmOut[ab0]);
            __builtin_nontemporal_store(sp1, &AmOut[ab1]);
            v0 *= (1.0f - sp0);
            v1 *= (1.0f - sp1);
            tk0 = tau0; tk1 = tau1;
            t0i = __float_as_int(tau0);
            t1i = __float_as_int(tau1);
            ab0 += D_; ab1 += D_;
            a0_pf = a0_nx; m0_pf = m0_nx;
            a1_pf = a1_nx; m1_pf = m1_nx;
        }
        // no second barrier: part[par^1] is written next; part[par] reuse at
        // c+2 is ordered through publish(c) -> partners' poll -> their c+1.
    }

    if (self) {
        const size_t b0 = bp * 2, b1 = bp * 2 + 1;
        OutTail[(size_t)BT_ * D_ + b0 * D_ + gch] = tk0;
        OutTail[(size_t)BT_ * D_ + b1 * D_ + gch] = tk1;
        OutTail[(size_t)BT_ * D_ + (size_t)B_ * D_ + b0 * D_ + gch] = v0;
        OutTail[(size_t)BT_ * D_ + (size_t)B_ * D_ + b1 * D_ + gch] = v1;
    }
}

// ---------------------------------------------------------------------------
extern "C" void kernel_launch(void* const* d_in, const int* in_sizes, int n_in,
                              void* d_out, int out_size, void* d_ws, size_t ws_size,
                              hipStream_t stream) {
    (void)in_sizes; (void)n_in; (void)out_size; (void)ws_size;
    const float* x          = (const float*)d_in[0];
    const float* tau_w      = (const float*)d_in[1];
    const float* tau_b      = (const float*)d_in[2];
    const float* mem_w      = (const float*)d_in[3];
    const float* mem_b      = (const float*)d_in[4];
    const float* log_thresh = (const float*)d_in[5];
    float* out = (float*)d_out;

    // workspace layout
    float* Wcat = (float*)d_ws;            // 512*1024 (dead after GEMM)
    float* WTh  = Wcat + 512 * 1024;       // 512*512
    float* Mout = WTh + 512 * 512;         // 131072*512
    // sync state reuses the Wcat region (GEMM finishes before init_sync)
    u64* xchg = (u64*)d_ws;                           // 2*XWORDS*8 = 512 KB
    int* ctr  = (int*)((char*)d_ws + 2 * XWORDS * sizeof(u64));

    float* Aout = out;                     // spikes region doubles as A buffer

    prep_weights<<<2048, 256, 0, stream>>>(tau_w, mem_w, Wcat, WTh);
    gemm_xw<<<dim3(8, 1024), 256, 0, stream>>>(x, Wcat, tau_b, mem_b, Aout, Mout);
    init_sync<<<256, 256, 0, stream>>>(xchg, ctr);

    const float* WThc = WTh;
    const float* Mmc  = Mout;
    const float* ltc  = log_thresh;
    float* outp = out;
    u64* xchgp = xchg;
    int* ctrp = ctr;
    void* args[7] = {(void*)&WThc, (void*)&Mmc, (void*)&ltc,
                     (void*)&Aout, (void*)&outp, (void*)&xchgp, (void*)&ctrp};
    hipLaunchCooperativeKernel((const void*)scan_ws, dim3(256), dim3(512),
                               args, 0, stream);
}